// Round 2
// baseline (752.410 us; speedup 1.0000x reference)
//
#include <hip/hip_runtime.h>
#include <hip/hip_bf16.h>
#include <math.h>

#define N_NODES 50000
#define N_EDGES 800000
#define IN_DIM 128
#define NEG_SLOPE 0.2f
// HEADS*HID = HEADS*OUT = 256 columns in both GEMMs

// ---------------- CSR build ----------------

__global__ void zero_int(int* __restrict__ p, int n) {
    int i = blockIdx.x * blockDim.x + threadIdx.x;
    if (i < n) p[i] = 0;
}

__global__ void hist_kernel(const int* __restrict__ dst, int* __restrict__ cnt) {
    int e = blockIdx.x * blockDim.x + threadIdx.x;
    if (e < N_EDGES) atomicAdd(&cnt[dst[e]], 1);
}

__global__ __launch_bounds__(1024) void scan_kernel(const int* __restrict__ cnt,
                                                    int* __restrict__ off, int n) {
    __shared__ int buf[1024];
    __shared__ int carry;
    int tid = threadIdx.x;
    if (tid == 0) carry = 0;
    __syncthreads();
    for (int base = 0; base < n; base += 1024) {
        int i = base + tid;
        int v = (i < n) ? cnt[i] : 0;
        buf[tid] = v;
        __syncthreads();
        for (int s = 1; s < 1024; s <<= 1) {
            int t = (tid >= s) ? buf[tid - s] : 0;
            __syncthreads();
            buf[tid] += t;
            __syncthreads();
        }
        if (i < n) off[i] = carry + buf[tid] - v;   // exclusive
        __syncthreads();
        if (tid == 0) carry += buf[1023];
        __syncthreads();
    }
    if (tid == 0) off[n] = carry;
}

__global__ void copy_int(const int* __restrict__ a, int* __restrict__ b, int n) {
    int i = blockIdx.x * blockDim.x + threadIdx.x;
    if (i < n) b[i] = a[i];
}

__global__ void scatter_kernel(const int* __restrict__ src, const int* __restrict__ dst,
                               int* __restrict__ cur, int* __restrict__ csr_src) {
    int e = blockIdx.x * blockDim.x + threadIdx.x;
    if (e < N_EDGES) {
        int d = dst[e];
        int pos = atomicAdd(&cur[d], 1);
        csr_src[pos] = src[e];
    }
}

// ---------------- GEMM: C[M,256] = A[M,K] * B[K,256] (fp32) ----------------

template <int K>
__global__ __launch_bounds__(256) void gemm_kernel(const float* __restrict__ A,
                                                   const float* __restrict__ B,
                                                   float* __restrict__ C, int M) {
    __shared__ float As[16][64];   // k-major
    __shared__ float Bs[16][64];
    int tid = threadIdx.x;
    int row0 = blockIdx.y * 64;
    int col0 = blockIdx.x * 64;
    int tm = tid >> 4, tn = tid & 15;

    // loader mapping
    int lm = tid >> 2;            // A: row within tile 0..63
    int lk = (tid & 3) * 4;       // A: k within tile {0,4,8,12}
    int lkb = tid >> 4;           // B: k within tile 0..15
    int lnb = (tid & 15) * 4;     // B: col within tile

    float acc[4][4] = {};

    for (int kb = 0; kb < K; kb += 16) {
        float4 av;
        int arow = row0 + lm;
        if (arow < M)
            av = *reinterpret_cast<const float4*>(&A[(size_t)arow * K + kb + lk]);
        else
            av = make_float4(0.f, 0.f, 0.f, 0.f);
        As[lk + 0][lm] = av.x;
        As[lk + 1][lm] = av.y;
        As[lk + 2][lm] = av.z;
        As[lk + 3][lm] = av.w;
        *reinterpret_cast<float4*>(&Bs[lkb][lnb]) =
            *reinterpret_cast<const float4*>(&B[(size_t)(kb + lkb) * 256 + col0 + lnb]);
        __syncthreads();
#pragma unroll
        for (int kk = 0; kk < 16; kk++) {
            float4 a = *reinterpret_cast<const float4*>(&As[kk][tm * 4]);
            float4 b = *reinterpret_cast<const float4*>(&Bs[kk][tn * 4]);
            acc[0][0] += a.x * b.x; acc[0][1] += a.x * b.y; acc[0][2] += a.x * b.z; acc[0][3] += a.x * b.w;
            acc[1][0] += a.y * b.x; acc[1][1] += a.y * b.y; acc[1][2] += a.y * b.z; acc[1][3] += a.y * b.w;
            acc[2][0] += a.z * b.x; acc[2][1] += a.z * b.y; acc[2][2] += a.z * b.z; acc[2][3] += a.z * b.w;
            acc[3][0] += a.w * b.x; acc[3][1] += a.w * b.y; acc[3][2] += a.w * b.z; acc[3][3] += a.w * b.w;
        }
        __syncthreads();
    }
#pragma unroll
    for (int i = 0; i < 4; i++) {
        int r = row0 + tm * 4 + i;
        if (r < M) {
            float4 v = make_float4(acc[i][0], acc[i][1], acc[i][2], acc[i][3]);
            *reinterpret_cast<float4*>(&C[(size_t)r * 256 + col0 + tn * 4]) = v;
        }
    }
}

// ---------------- el/er: per-(node,head) attention logits ----------------

__global__ __launch_bounds__(256) void elr_kernel(const float* __restrict__ feat,
                                                  const float* __restrict__ al,
                                                  const float* __restrict__ ar,
                                                  float* __restrict__ el,
                                                  float* __restrict__ er) {
    int n = blockIdx.x;
    int h = threadIdx.x >> 6;
    int lane = threadIdx.x & 63;
    float f = feat[(size_t)n * 256 + h * 64 + lane];
    float pl = f * al[h * 64 + lane];
    float pr = f * ar[h * 64 + lane];
#pragma unroll
    for (int s = 32; s > 0; s >>= 1) {
        pl += __shfl_xor(pl, s, 64);
        pr += __shfl_xor(pr, s, 64);
    }
    if (lane == 0) {
        el[n * 4 + h] = pl;
        er[n * 4 + h] = pr;
    }
}

// ---------------- per-node online-softmax aggregation ----------------
// wave h of the block handles head h of node blockIdx.x; lane = feature dim.

template <int LAYER>
__global__ __launch_bounds__(256) void agg_kernel(const float* __restrict__ feat,
                                                  const float* __restrict__ el,
                                                  const float* __restrict__ er,
                                                  const int* __restrict__ row_off,
                                                  const int* __restrict__ csr_src,
                                                  const float* __restrict__ bias,
                                                  float* __restrict__ out) {
    int n = blockIdx.x;
    int h = threadIdx.x >> 6;
    int lane = threadIdx.x & 63;
    int js = row_off[n], je = row_off[n + 1];
    float er_nh = er[n * 4 + h];
    float m = -INFINITY, ssum = 0.f, acc = 0.f;
    for (int j = js; j < je; j++) {
        int s = csr_src[j];
        float val = el[s * 4 + h] + er_nh;
        val = val >= 0.f ? val : NEG_SLOPE * val;
        float mn = fmaxf(m, val);
        float sc = __expf(m - mn);     // 0 when m == -inf
        float p = __expf(val - mn);
        ssum = ssum * sc + p;
        acc = acc * sc + p * feat[(size_t)s * 256 + h * 64 + lane];
        m = mn;
    }
    float res = acc / fmaxf(ssum, 1e-9f) + bias[h * 64 + lane];
    if (LAYER == 1) {
        res = res > 0.f ? res : __expf(res) - 1.f;   // elu
        out[(size_t)n * 256 + h * 64 + lane] = res;
    } else {
        __shared__ float red[256];
        red[threadIdx.x] = res;
        __syncthreads();
        if (h == 0) {
            float sum = red[lane] + red[64 + lane] + red[128 + lane] + red[192 + lane];
            out[(size_t)n * 64 + lane] = sum * 0.25f;
        }
    }
}

// ---------------- launch ----------------

extern "C" void kernel_launch(void* const* d_in, const int* in_sizes, int n_in,
                              void* d_out, int out_size, void* d_ws, size_t ws_size,
                              hipStream_t stream) {
    const float* features = (const float*)d_in[0];
    const int*   src      = (const int*)d_in[1];
    const int*   dst      = (const int*)d_in[2];
    const float* W1       = (const float*)d_in[3];
    const float* al1      = (const float*)d_in[4];
    const float* ar1      = (const float*)d_in[5];
    const float* b1       = (const float*)d_in[6];
    const float* W2       = (const float*)d_in[7];
    const float* al2      = (const float*)d_in[8];
    const float* ar2      = (const float*)d_in[9];
    const float* b2       = (const float*)d_in[10];
    float* out = (float*)d_out;

    char* ws = (char*)d_ws;
    float* feat    = (float*)(ws);                    // 51,200,000 B
    float* h1      = (float*)(ws + 51200000);         // 51,200,000 B
    float* el      = (float*)(ws + 102400000);        //    800,000 B
    float* er      = (float*)(ws + 103200000);        //    800,000 B
    int*   row_off = (int*)  (ws + 104000000);        //    200,064 B
    int*   cur     = (int*)  (ws + 104200064);        //    200,000 B
    int*   csr     = (int*)  (ws + 104400064);        //  3,200,000 B

    // --- CSR build (graph shared by both layers) ---
    zero_int<<<(N_NODES + 255) / 256, 256, 0, stream>>>(cur, N_NODES);
    hist_kernel<<<(N_EDGES + 255) / 256, 256, 0, stream>>>(dst, cur);
    scan_kernel<<<1, 1024, 0, stream>>>(cur, row_off, N_NODES);
    copy_int<<<(N_NODES + 255) / 256, 256, 0, stream>>>(row_off, cur, N_NODES);
    scatter_kernel<<<(N_EDGES + 255) / 256, 256, 0, stream>>>(src, dst, cur, csr);

    dim3 gemm_grid(4, (N_NODES + 63) / 64);

    // --- layer 1 ---
    gemm_kernel<IN_DIM><<<gemm_grid, 256, 0, stream>>>(features, W1, feat, N_NODES);
    elr_kernel<<<N_NODES, 256, 0, stream>>>(feat, al1, ar1, el, er);
    agg_kernel<1><<<N_NODES, 256, 0, stream>>>(feat, el, er, row_off, csr, b1, h1);

    // --- layer 2 ---
    gemm_kernel<256><<<gemm_grid, 256, 0, stream>>>(h1, W2, feat, N_NODES);
    elr_kernel<<<N_NODES, 256, 0, stream>>>(feat, al2, ar2, el, er);
    agg_kernel<2><<<N_NODES, 256, 0, stream>>>(feat, el, er, row_off, csr, b2, out);
}

// Round 3
// 541.199 us; speedup vs baseline: 1.3903x; 1.3903x over previous
//
#include <hip/hip_runtime.h>
#include <hip/hip_bf16.h>
#include <math.h>

#define N_NODES 50000
#define N_EDGES 800000
#define IN_DIM 128
#define NEG_SLOPE 0.2f
// HEADS*HID = HEADS*OUT = 256 columns in both GEMMs

__device__ inline unsigned short f2bf(float v) {   // RNE fp32->bf16
    unsigned u = __float_as_uint(v);
    unsigned r = (u + 0x7fffu + ((u >> 16) & 1u)) >> 16;
    return (unsigned short)r;
}
__device__ inline float bf2f(unsigned short b) {
    return __uint_as_float(((unsigned)b) << 16);
}

// ---------------- CSR build ----------------

__global__ void zero_int(int* __restrict__ p, int n) {
    int i = blockIdx.x * blockDim.x + threadIdx.x;
    if (i < n) p[i] = 0;
}

__global__ void hist_kernel(const int* __restrict__ dst, int* __restrict__ cnt) {
    int e = blockIdx.x * blockDim.x + threadIdx.x;
    if (e < N_EDGES) atomicAdd(&cnt[dst[e]], 1);
}

// single-block scan, wave-shuffle based (2 barriers per 1024-tile)
__global__ __launch_bounds__(1024) void scan_kernel(const int* __restrict__ cnt,
                                                    int* __restrict__ off, int n) {
    __shared__ int wsum[16];
    __shared__ int carry_s;
    int tid = threadIdx.x, wid = tid >> 6, lane = tid & 63;
    if (tid == 0) carry_s = 0;
    __syncthreads();
    for (int base = 0; base < n; base += 1024) {
        int i = base + tid;
        int v = (i < n) ? cnt[i] : 0;
        int x = v;
#pragma unroll
        for (int s = 1; s < 64; s <<= 1) {
            int t = __shfl_up(x, s, 64);
            if (lane >= s) x += t;
        }
        if (lane == 63) wsum[wid] = x;
        __syncthreads();
        if (wid == 0 && lane < 16) {
            int w = wsum[lane];
#pragma unroll
            for (int s = 1; s < 16; s <<= 1) {
                int t = __shfl_up(w, s, 64);
                if (lane >= s) w += t;
            }
            wsum[lane] = w;   // inclusive scan of wave sums
        }
        __syncthreads();
        int woff = (wid > 0) ? wsum[wid - 1] : 0;
        int incl = carry_s + woff + x;
        if (i < n) off[i] = incl - v;   // exclusive
        __syncthreads();
        if (tid == 1023) carry_s = incl;
        __syncthreads();
    }
    if (threadIdx.x == 0) off[n] = carry_s;
}

__global__ void copy_int(const int* __restrict__ a, int* __restrict__ b, int n) {
    int i = blockIdx.x * blockDim.x + threadIdx.x;
    if (i < n) b[i] = a[i];
}

__global__ void scatter_kernel(const int* __restrict__ src, const int* __restrict__ dst,
                               int* __restrict__ cur, int* __restrict__ csr_src) {
    int e = blockIdx.x * blockDim.x + threadIdx.x;
    if (e < N_EDGES) {
        int d = dst[e];
        int pos = atomicAdd(&cur[d], 1);
        csr_src[pos] = src[e];
    }
}

// ---------------- GEMM: C[M,256] = A[M,K]*B[K,256], fp32 + bf16 copy ----------------

template <int K>
__global__ __launch_bounds__(256) void gemm_kernel(const float* __restrict__ A,
                                                   const float* __restrict__ B,
                                                   float* __restrict__ C,
                                                   unsigned short* __restrict__ C16,
                                                   int M) {
    __shared__ float As[16][64];   // k-major
    __shared__ float Bs[16][64];
    int tid = threadIdx.x;
    int row0 = blockIdx.y * 64;
    int col0 = blockIdx.x * 64;
    int tm = tid >> 4, tn = tid & 15;

    int lm = tid >> 2;            // A: row within tile 0..63
    int lk = (tid & 3) * 4;       // A: k within tile {0,4,8,12}
    int lkb = tid >> 4;           // B: k within tile 0..15
    int lnb = (tid & 15) * 4;     // B: col within tile

    float acc[4][4] = {};

    for (int kb = 0; kb < K; kb += 16) {
        float4 av;
        int arow = row0 + lm;
        if (arow < M)
            av = *reinterpret_cast<const float4*>(&A[(size_t)arow * K + kb + lk]);
        else
            av = make_float4(0.f, 0.f, 0.f, 0.f);
        As[lk + 0][lm] = av.x;
        As[lk + 1][lm] = av.y;
        As[lk + 2][lm] = av.z;
        As[lk + 3][lm] = av.w;
        *reinterpret_cast<float4*>(&Bs[lkb][lnb]) =
            *reinterpret_cast<const float4*>(&B[(size_t)(kb + lkb) * 256 + col0 + lnb]);
        __syncthreads();
#pragma unroll
        for (int kk = 0; kk < 16; kk++) {
            float4 a = *reinterpret_cast<const float4*>(&As[kk][tm * 4]);
            float4 b = *reinterpret_cast<const float4*>(&Bs[kk][tn * 4]);
            acc[0][0] += a.x * b.x; acc[0][1] += a.x * b.y; acc[0][2] += a.x * b.z; acc[0][3] += a.x * b.w;
            acc[1][0] += a.y * b.x; acc[1][1] += a.y * b.y; acc[1][2] += a.y * b.z; acc[1][3] += a.y * b.w;
            acc[2][0] += a.z * b.x; acc[2][1] += a.z * b.y; acc[2][2] += a.z * b.z; acc[2][3] += a.z * b.w;
            acc[3][0] += a.w * b.x; acc[3][1] += a.w * b.y; acc[3][2] += a.w * b.z; acc[3][3] += a.w * b.w;
        }
        __syncthreads();
    }
#pragma unroll
    for (int i = 0; i < 4; i++) {
        int r = row0 + tm * 4 + i;
        if (r < M) {
            float4 v = make_float4(acc[i][0], acc[i][1], acc[i][2], acc[i][3]);
            *reinterpret_cast<float4*>(&C[(size_t)r * 256 + col0 + tn * 4]) = v;
            ushort4 u;
            u.x = f2bf(v.x); u.y = f2bf(v.y); u.z = f2bf(v.z); u.w = f2bf(v.w);
            *reinterpret_cast<ushort4*>(&C16[(size_t)r * 256 + col0 + tn * 4]) = u;
        }
    }
}

// ---------------- el/er: per-(node,head) attention logits ----------------

__global__ __launch_bounds__(256) void elr_kernel(const float* __restrict__ feat,
                                                  const float* __restrict__ al,
                                                  const float* __restrict__ ar,
                                                  float* __restrict__ el,
                                                  float* __restrict__ er) {
    int n = blockIdx.x;
    int h = threadIdx.x >> 6;
    int lane = threadIdx.x & 63;
    float f = feat[(size_t)n * 256 + h * 64 + lane];
    float pl = f * al[h * 64 + lane];
    float pr = f * ar[h * 64 + lane];
#pragma unroll
    for (int s = 32; s > 0; s >>= 1) {
        pl += __shfl_xor(pl, s, 64);
        pr += __shfl_xor(pr, s, 64);
    }
    if (lane == 0) {
        el[n * 4 + h] = pl;
        er[n * 4 + h] = pr;
    }
}

// ---------------- aggregation: one wave per node, all 4 heads ----------------
// lane l holds features l*4..l*4+3 of the 256-wide row; head h = l>>4.

template <int LAYER>
__global__ __launch_bounds__(256) void agg_kernel(const unsigned short* __restrict__ feat16,
                                                  const float* __restrict__ el,
                                                  const float* __restrict__ er,
                                                  const int* __restrict__ row_off,
                                                  const int* __restrict__ csr_src,
                                                  const float* __restrict__ bias,
                                                  float* __restrict__ out) {
    int n = blockIdx.x * 4 + (threadIdx.x >> 6);   // 12500 blocks * 4 waves = 50000
    int lane = threadIdx.x & 63;
    int h = lane >> 4;
    int js = row_off[n], je = row_off[n + 1];
    float er_nh = er[n * 4 + h];
    float m = -INFINITY, ssum = 0.f;
    float4 acc = make_float4(0.f, 0.f, 0.f, 0.f);
    for (int j = js; j < je; j++) {
        int s = csr_src[j];
        float val = el[s * 4 + h] + er_nh;
        val = val >= 0.f ? val : NEG_SLOPE * val;
        float mn = fmaxf(m, val);
        float sc = __expf(m - mn);     // 0 when m == -inf
        float p = __expf(val - mn);
        ssum = ssum * sc + p;
        ushort4 u = *reinterpret_cast<const ushort4*>(&feat16[(size_t)s * 256 + lane * 4]);
        acc.x = acc.x * sc + p * bf2f(u.x);
        acc.y = acc.y * sc + p * bf2f(u.y);
        acc.z = acc.z * sc + p * bf2f(u.z);
        acc.w = acc.w * sc + p * bf2f(u.w);
        m = mn;
    }
    float inv = 1.f / fmaxf(ssum, 1e-9f);
    // bias index: h*64 + (lane&15)*4 + i == lane*4 + i
    float4 res;
    res.x = acc.x * inv + bias[lane * 4 + 0];
    res.y = acc.y * inv + bias[lane * 4 + 1];
    res.z = acc.z * inv + bias[lane * 4 + 2];
    res.w = acc.w * inv + bias[lane * 4 + 3];
    if (LAYER == 1) {
        res.x = res.x > 0.f ? res.x : __expf(res.x) - 1.f;
        res.y = res.y > 0.f ? res.y : __expf(res.y) - 1.f;
        res.z = res.z > 0.f ? res.z : __expf(res.z) - 1.f;
        res.w = res.w > 0.f ? res.w : __expf(res.w) - 1.f;
        *reinterpret_cast<float4*>(&out[(size_t)n * 256 + lane * 4]) = res;
    } else {
        // mean over heads: feature f is held by lanes {f>>2, +16, +32, +48}
#pragma unroll
        for (int mask = 16; mask <= 32; mask <<= 1) {
            res.x += __shfl_xor(res.x, mask, 64);
            res.y += __shfl_xor(res.y, mask, 64);
            res.z += __shfl_xor(res.z, mask, 64);
            res.w += __shfl_xor(res.w, mask, 64);
        }
        if (lane < 16) {
            float4 o = make_float4(res.x * 0.25f, res.y * 0.25f, res.z * 0.25f, res.w * 0.25f);
            *reinterpret_cast<float4*>(&out[(size_t)n * 64 + lane * 4]) = o;
        }
    }
}

// ---------------- launch ----------------

extern "C" void kernel_launch(void* const* d_in, const int* in_sizes, int n_in,
                              void* d_out, int out_size, void* d_ws, size_t ws_size,
                              hipStream_t stream) {
    const float* features = (const float*)d_in[0];
    const int*   src      = (const int*)d_in[1];
    const int*   dst      = (const int*)d_in[2];
    const float* W1       = (const float*)d_in[3];
    const float* al1      = (const float*)d_in[4];
    const float* ar1      = (const float*)d_in[5];
    const float* b1       = (const float*)d_in[6];
    const float* W2       = (const float*)d_in[7];
    const float* al2      = (const float*)d_in[8];
    const float* ar2      = (const float*)d_in[9];
    const float* b2       = (const float*)d_in[10];
    float* out = (float*)d_out;

    char* ws = (char*)d_ws;
    float*          feat    = (float*)(ws);                    // 51,200,000 B
    float*          h1      = (float*)(ws + 51200000);         // 51,200,000 B
    unsigned short* feat16  = (unsigned short*)(ws + 102400000); // 25,600,000 B
    float*          el      = (float*)(ws + 128000000);        //    800,000 B
    float*          er      = (float*)(ws + 128800000);        //    800,000 B
    int*            row_off = (int*)  (ws + 129600000);        //    200,064 B
    int*            cur     = (int*)  (ws + 129800064);        //    200,000 B
    int*            csr     = (int*)  (ws + 130000064);        //  3,200,000 B

    // --- CSR build (graph shared by both layers) ---
    zero_int<<<(N_NODES + 255) / 256, 256, 0, stream>>>(cur, N_NODES);
    hist_kernel<<<(N_EDGES + 255) / 256, 256, 0, stream>>>(dst, cur);
    scan_kernel<<<1, 1024, 0, stream>>>(cur, row_off, N_NODES);
    copy_int<<<(N_NODES + 255) / 256, 256, 0, stream>>>(row_off, cur, N_NODES);
    scatter_kernel<<<(N_EDGES + 255) / 256, 256, 0, stream>>>(src, dst, cur, csr);

    dim3 gemm_grid(4, (N_NODES + 63) / 64);

    // --- layer 1 ---
    gemm_kernel<IN_DIM><<<gemm_grid, 256, 0, stream>>>(features, W1, feat, feat16, N_NODES);
    elr_kernel<<<N_NODES, 256, 0, stream>>>(feat, al1, ar1, el, er);
    agg_kernel<1><<<12500, 256, 0, stream>>>(feat16, el, er, row_off, csr, b1, h1);

    // --- layer 2 ---
    gemm_kernel<256><<<gemm_grid, 256, 0, stream>>>(h1, W2, feat, feat16, N_NODES);
    elr_kernel<<<N_NODES, 256, 0, stream>>>(feat, al2, ar2, el, er);
    agg_kernel<2><<<12500, 256, 0, stream>>>(feat16, el, er, row_off, csr, b2, out);
}